// Round 14
// baseline (74.037 us; speedup 1.0000x reference)
//
#include <hip/hip_runtime.h>
#include <hip/hip_bf16.h>
#include <math.h>
#include <stdint.h>

// Problem constants
#define NCH   8
#define DNX   128
#define DNY   128
#define KPTS  16384

typedef __attribute__((ext_vector_type(8)))  short bf16x8;   // MFMA A/B frag (8 bf16)
typedef __attribute__((ext_vector_type(16))) float f32x16;   // 32x32 MFMA C/D frag

// pack two fp32 -> one uint32 of two bf16 (RNE)
__device__ __forceinline__ uint32_t pkbf(float lo, float hi) {
    union { __hip_bfloat162 h; uint32_t u; } v;
    v.h = __float22bfloat162_rn(make_float2(lo, hi));
    return v.u;
}

// ---------------------------------------------------------------------------
// Round-14: SINGLE-DISPATCH. The prep kernel's fold+pack (verified r11-r13)
// is fused into main's prologue: each block re-folds its own channel into
// LDS directly (64x redundant compute across kb-blocks, but prologue VALU is
// free slack — r10 proved a 2.3x VALU cut is time-neutral — and this deletes
// the prep dispatch + inter-kernel gap + the B_pre L2 round-trip).
// Everything after the fold is VERBATIM from the passing r13:
//  * center-symmetric x-fold: contraction 64, MFMA count halved (r11 win),
//    epilogue rotation cis(pi*tx/128).
//  * in-kernel folded phase fragments (r12), one k-set per wave, ~118 VGPR,
//    (512,2) -> 4 waves/SIMD (r13).
//  * LDS layout B[x_slot][col], col = 2y+s, addr =
//    (256*col + 64*t4 + 16*q) ^ (16*(col&7)); per-lane pre-XOR'd bases.
//  * stage-2 lane-local rotor combine; shfl_xor(32) epilogue.
// Evidence summary r0-r13: main is insensitive to MFMA x2 / VALU x2.3 /
// LDS x2 / occupancy x2 / barrier scheduling; residue = post-fill clock
// regime + fixed per-launch costs. This round removes the last fixed cost.
// ---------------------------------------------------------------------------
__global__ __launch_bounds__(512, 2) void nudft_mfma_kernel(
    const float* __restrict__ trj,
    const float* __restrict__ img_real,
    const float* __restrict__ img_imag,
    float* __restrict__ out)
{
    __shared__ __align__(16) unsigned short Bl[32768];   // 64 KB folded channel

    const int t    = threadIdx.x;     // 0..511
    const int w    = t >> 6;          // wave 0..7
    const int lane = t & 63;
    const int l31  = lane & 31;
    const int hi   = lane >> 5;
    const int kb   = blockIdx.x;      // 0..63
    const int c    = blockIdx.y;      // 0..7
    const int k    = kb * 256 + w * 32 + l31;   // this lane's k-point

    // ---- trj loads first
    const float tx = trj[2 * k];
    const float ty = trj[2 * k + 1];

    // ---- FUSED fold+pack (prep's exact math): fill Bl with folded channel c.
    // tid2 = seg*512 + t in [0,2048): y = tid2&127, uc = (tid2>>7)&7,
    // s = tid2>>10. f_plus -> x-slot 8uc (t4p), f_minus -> x-slot 64+8uc.
    #pragma unroll
    for (int seg = 0; seg < 4; ++seg) {
        int tid2 = seg * 512 + t;
        int y  = tid2 & 127;
        int uc = (tid2 >> 7) & 7;
        int s  = tid2 >> 10;
        int u0 = 8 * uc;
        const float* src = (s ? img_imag : img_real) + c * (DNX * DNY) + y;
        float fp[8], fm[8];
        #pragma unroll
        for (int j = 0; j < 8; ++j) {
            float a = src[(64 + u0 + j) * DNY];
            float b = src[(63 - u0 - j) * DNY];
            fp[j] = a + b;
            fm[j] = a - b;
        }
        int col = 2 * y + s;
        int xo  = 16 * (col & 7);
        int t4p = uc >> 2, q = uc & 3;
        int destp = (256 * col + 64 * t4p       + 16 * q) ^ xo;   // slot u0
        int destm = (256 * col + 64 * (t4p + 2) + 16 * q) ^ xo;   // slot 64+u0
        uint4 vp, vm;
        vp.x = pkbf(fp[0], fp[1]); vp.y = pkbf(fp[2], fp[3]);
        vp.z = pkbf(fp[4], fp[5]); vp.w = pkbf(fp[6], fp[7]);
        vm.x = pkbf(fm[0], fm[1]); vm.y = pkbf(fm[2], fm[3]);
        vm.z = pkbf(fm[4], fm[5]); vm.w = pkbf(fm[6], fm[7]);
        *(uint4*)((char*)&Bl[0] + destp) = vp;
        *(uint4*)((char*)&Bl[0] + destm) = vm;
    }

    // ---- folded phase fragments, in-kernel (r12/r13's verified math).
    // Fragment element (m, hi, j): angle = pi * d1 * (16m + 8hi + j + 0.5),
    // d1 = -tx/64. cos -> pc[m], sin -> psn[m].
    bf16x8 pc[4], psn[4];
    {
        const float d1 = -tx * (1.0f / 64.0f);
        float s1, c1;   sincospif(d1, &s1, &c1);            // step per +1
        float s16, c16; sincospif(16.0f * d1, &s16, &c16);  // step per +16 (m)
        float ps, pcv;  sincospif(d1 * ((float)(8 * hi) + 0.5f), &ps, &pcv);
        #pragma unroll
        for (int m = 0; m < 4; ++m) {
            float qc = pcv, qs = ps;
            float fc[8], fs[8];
            #pragma unroll
            for (int j = 0; j < 8; ++j) {
                fc[j] = qc; fs[j] = qs;
                if (j < 7) {
                    float tq = qc * c1 - qs * s1;
                    qs = fmaf(qc, s1, qs * c1);
                    qc = tq;
                }
            }
            uint32_t* pr = (uint32_t*)&pc[m];
            uint32_t* pi = (uint32_t*)&psn[m];
            #pragma unroll
            for (int p = 0; p < 4; ++p) {
                pr[p] = pkbf(fc[2 * p], fc[2 * p + 1]);
                pi[p] = pkbf(fs[2 * p], fs[2 * p + 1]);
            }
            if (m < 3) {
                float tp = pcv * c16 - ps * s16;
                ps  = fmaf(pcv, s16, ps * c16);
                pcv = tp;
            }
        }
    }

    // ---- final per-k rotation cis(pi*tx/128)
    float srR, crR; sincospif(tx * 0.0078125f, &srR, &crR);

    // ---- stage-2 rotors (verified r10-r13 form)
    float rdi, rdr; sincospif(-ty * 0.25f, &rdi, &rdr);
    float cb[8], sb[8];
    {
        float bs, bc; sincospif(-ty * (float)(2 * hi - 64) * (1.0f / 64.0f), &bs, &bc);
        float qs4, qc4; sincospif(-ty * 0.0625f,   &qs4, &qc4);
        float os1, oc1; sincospif(-ty * 0.015625f, &os1, &oc1);
        float rc = bc, rs = bs;
        #pragma unroll
        for (int q = 0; q < 4; ++q) {
            cb[2 * q] = rc;  sb[2 * q] = rs;
            cb[2 * q + 1] = rc * oc1 - rs * os1;
            sb[2 * q + 1] = fmaf(rc, os1, rs * oc1);
            if (q < 3) {
                float tz = rc * qc4 - rs * qs4;
                rs = fmaf(rc, qs4, rs * qc4);
                rc = tz;
            }
        }
    }
    float ore = 0.f, oim = 0.f;

    // ---- per-lane LDS bases (identical derivation to r7/r10-r13)
    const int s7 = lane & 7;
    const int u  = s7 >> 1;
    const int v  = hi ^ (s7 & 1);
    const char* baseA = (const char*)&Bl[0] + 256 * l31 + 16 * v;
    const char* B0 = baseA + 32 * (0 ^ u);
    const char* B1 = baseA + 32 * (1 ^ u);
    const char* B2 = baseA + 32 * (2 ^ u);
    const char* B3 = baseA + 32 * (3 ^ u);
    const f32x16 ZER16 = {0.f,0.f,0.f,0.f,0.f,0.f,0.f,0.f,
                          0.f,0.f,0.f,0.f,0.f,0.f,0.f,0.f};

    __syncthreads();   // fold writes visible; the ONLY barrier

    #pragma unroll 1
    for (int ct = 0; ct < 8; ++ct) {
        const int off = 8192 * ct;
        bf16x8 f0 = *(const bf16x8*)(B0 + off);          // plus-plane chunks
        bf16x8 f1 = *(const bf16x8*)(B1 + off);
        bf16x8 f2 = *(const bf16x8*)(B2 + off);
        bf16x8 f3 = *(const bf16x8*)(B3 + off);
        bf16x8 f4 = *(const bf16x8*)(B0 + off + 128);    // minus-plane chunks
        bf16x8 f5 = *(const bf16x8*)(B1 + off + 128);
        bf16x8 f6 = *(const bf16x8*)(B2 + off + 128);
        bf16x8 f7 = *(const bf16x8*)(B3 + off + 128);
        f32x16 a1, a2;
        __builtin_amdgcn_s_setprio(1);
        a1 = __builtin_amdgcn_mfma_f32_32x32x16_bf16(f0, pc[0],  ZER16, 0,0,0);
        a2 = __builtin_amdgcn_mfma_f32_32x32x16_bf16(f4, psn[0], ZER16, 0,0,0);
        a1 = __builtin_amdgcn_mfma_f32_32x32x16_bf16(f1, pc[1],  a1,    0,0,0);
        a2 = __builtin_amdgcn_mfma_f32_32x32x16_bf16(f5, psn[1], a2,    0,0,0);
        a1 = __builtin_amdgcn_mfma_f32_32x32x16_bf16(f2, pc[2],  a1,    0,0,0);
        a2 = __builtin_amdgcn_mfma_f32_32x32x16_bf16(f6, psn[2], a2,    0,0,0);
        a1 = __builtin_amdgcn_mfma_f32_32x32x16_bf16(f3, pc[3],  a1,    0,0,0);
        a2 = __builtin_amdgcn_mfma_f32_32x32x16_bf16(f7, psn[3], a2,    0,0,0);
        __builtin_amdgcn_s_setprio(0);
        // stage 2 (combine signs verified r7/r10-r13)
        #pragma unroll
        for (int q = 0; q < 4; ++q) {
            #pragma unroll
            for (int j = 0; j < 2; ++j) {
                const int e = 4 * q + 2 * j;
                const int p = 2 * q + j;
                float Sre = a1[e]     - a2[e + 1];
                float Sim = a1[e + 1] + a2[e];
                ore = fmaf(Sre,  cb[p], ore);
                ore = fmaf(-Sim, sb[p], ore);
                oim = fmaf(Sre,  sb[p], oim);
                oim = fmaf(Sim,  cb[p], oim);
            }
        }
        // advance rotors (y += 16)
        #pragma unroll
        for (int p = 0; p < 8; ++p) {
            float tz = cb[p] * rdr - sb[p] * rdi;
            sb[p] = fmaf(cb[p], rdi, sb[p] * rdr);
            cb[p] = tz;
        }
    }

    // ---- epilogue: fold lane-halves, apply final rotation cis(pi*tx/128)
    {
        float r0 = ore + __shfl_xor(ore, 32);
        float i0 = oim + __shfl_xor(oim, 32);
        if (lane < 32) {
            out[(size_t)c * KPTS + k]                      = r0 * crR - i0 * srR;
            out[(size_t)NCH * KPTS + (size_t)c * KPTS + k] = fmaf(r0, srR, i0 * crR);
        }
    }
}

extern "C" void kernel_launch(void* const* d_in, const int* in_sizes, int n_in,
                              void* d_out, int out_size, void* d_ws, size_t ws_size,
                              hipStream_t stream)
{
    const float* img_real = (const float*)d_in[0];  // (8,128,128) fp32
    const float* img_imag = (const float*)d_in[1];  // (8,128,128) fp32
    const float* trj      = (const float*)d_in[2];  // (16384,2) fp32
    float* out = (float*)d_out;                      // planar: re block then im block

    // single dispatch — prep fused into the main kernel's prologue
    nudft_mfma_kernel<<<dim3(64, 8), 512, 0, stream>>>(trj, img_real, img_imag, out);
}

// Round 15
// 73.224 us; speedup vs baseline: 1.0111x; 1.0111x over previous
//
#include <hip/hip_runtime.h>
#include <hip/hip_bf16.h>
#include <math.h>
#include <stdint.h>

// Problem constants
#define NCH   8
#define DNX   128
#define DNY   128
#define KPTS  16384

typedef __attribute__((ext_vector_type(8)))  short bf16x8;   // MFMA A/B frag (8 bf16)
typedef __attribute__((ext_vector_type(16))) float f32x16;   // 32x32 MFMA C/D frag

typedef const __attribute__((address_space(1))) unsigned int* gp_t;
typedef __attribute__((address_space(3))) unsigned int* lp_t;

// pack two fp32 -> one uint32 of two bf16 (RNE)
__device__ __forceinline__ uint32_t pkbf(float lo, float hi) {
    union { __hip_bfloat162 h; uint32_t u; } v;
    v.h = __float22bfloat162_rn(make_float2(lo, hi));
    return v.u;
}

// ---------------------------------------------------------------------------
// FINAL (= round-13, session best: 73.06us, absmax 4.0).
// Session summary (15 rounds):
//  * window = fill 40.3us (harness 256MB re-poison at 83% HBM peak,
//    untouchable) + main ~28us + prep/gap ~4us.
//  * main is MFMA/clock-regime floored: r8 triple-launch measured warm
//    marginal 25us == MFMA-cyc/SIMD at the ~650MHz post-fill clock exactly;
//    insensitive to VALU x2.3 (r10), LDS x2 (r13), occupancy x2 (r4/r6/r13),
//    barrier scheduling (r0/r2), desync (r5). The one real win was halving
//    MFMA FLOPs via the center-symmetric x-fold (r11: -6.5us).
//  * r14 (prep fused into main) was +1us — fold serializes ahead of the
//    barrier where the DMA used to overlap trig; reverted.
// Structure:
//  * prep: center-symmetric x-fold, f± planes packed bf16 into B_pre in the
//    exact LDS layout (addr = (256*col + 64*t4 + 16*q) ^ 16*(col&7)).
//  * main: one channel/block staged once via global_load_lds; 32x32x16 MFMA,
//    A = folded img tile (32 ycols x 16 u), B = in-kernel folded phase frags
//    (angle = pi*d1*(16m+8hi+j+0.5)); contraction 64; stage-2 lane-local
//    rotor combine; epilogue shfl_xor(32) + final rotation cis(pi*tx/128).
//  * (512,2) -> 4 waves/SIMD at ~118 VGPR, spill-free; single barrier.
// ---------------------------------------------------------------------------
__global__ __launch_bounds__(256) void prep_kernel(
    const float* __restrict__ img_real,
    const float* __restrict__ img_imag,
    unsigned short* __restrict__ B_pre)
{
    int tid = blockIdx.x * 256 + threadIdx.x;   // 16384 threads total
    int y  = tid & 127;
    int uc = (tid >> 7) & 7;                    // u-chunk 0..7, u0 = 8*uc
    int s  = (tid >> 10) & 1;
    int c  = tid >> 11;
    int u0 = 8 * uc;
    const float* src = (s ? img_imag : img_real) + c * (DNX * DNY) + y;
    float fp[8], fm[8];
    #pragma unroll
    for (int j = 0; j < 8; ++j) {
        float a = src[(64 + u0 + j) * DNY];
        float b = src[(63 - u0 - j) * DNY];
        fp[j] = a + b;
        fm[j] = a - b;
    }
    int col = 2 * y + s;
    int xo  = 16 * (col & 7);
    int t4p = uc >> 2, q = uc & 3;
    int destp = (256 * col + 64 * t4p       + 16 * q) ^ xo;   // slot u0
    int destm = (256 * col + 64 * (t4p + 2) + 16 * q) ^ xo;   // slot 64+u0
    uint4 vp, vm;
    vp.x = pkbf(fp[0], fp[1]); vp.y = pkbf(fp[2], fp[3]);
    vp.z = pkbf(fp[4], fp[5]); vp.w = pkbf(fp[6], fp[7]);
    vm.x = pkbf(fm[0], fm[1]); vm.y = pkbf(fm[2], fm[3]);
    vm.z = pkbf(fm[4], fm[5]); vm.w = pkbf(fm[6], fm[7]);
    char* base = (char*)B_pre + (size_t)c * 65536;
    *(uint4*)(base + destp) = vp;
    *(uint4*)(base + destm) = vm;
}

__global__ __launch_bounds__(512, 2) void nudft_mfma_kernel(
    const float* __restrict__ trj,
    const unsigned short* __restrict__ B_pre,
    float* __restrict__ out)
{
    __shared__ __align__(16) unsigned short Bl[32768];   // 64 KB folded channel

    const int t    = threadIdx.x;     // 0..511
    const int w    = t >> 6;          // wave 0..7
    const int lane = t & 63;
    const int l31  = lane & 31;
    const int hi   = lane >> 5;
    const int kb   = blockIdx.x;      // 0..63
    const int c    = blockIdx.y;      // 0..7
    const int k    = kb * 256 + w * 32 + l31;   // this lane's k-point

    // ---- trj loads first
    const float tx = trj[2 * k];
    const float ty = trj[2 * k + 1];

    // ---- stage the whole 64KB folded channel image (DMA overlaps the trig)
    {
        const char* g = (const char*)B_pre + ((size_t)c << 16) + (t << 4);
        char* l = (char*)&Bl[0] + (t << 4);
        #pragma unroll
        for (int i = 0; i < 8; ++i)
            __builtin_amdgcn_global_load_lds(
                (gp_t)(const void*)(g + (i << 13)),
                (lp_t)(void*)(l + (i << 13)), 16, 0, 0);
    }
    __builtin_amdgcn_sched_barrier(0);

    // ---- folded phase fragments, in-kernel.
    // Fragment element (m, hi, j): angle = pi * d1 * (16m + 8hi + j + 0.5),
    // d1 = -tx/64. cos -> pc[m], sin -> psn[m].
    bf16x8 pc[4], psn[4];
    {
        const float d1 = -tx * (1.0f / 64.0f);
        float s1, c1;   sincospif(d1, &s1, &c1);            // step per +1
        float s16, c16; sincospif(16.0f * d1, &s16, &c16);  // step per +16 (m)
        float ps, pcv;  sincospif(d1 * ((float)(8 * hi) + 0.5f), &ps, &pcv);
        #pragma unroll
        for (int m = 0; m < 4; ++m) {
            float qc = pcv, qs = ps;
            float fc[8], fs[8];
            #pragma unroll
            for (int j = 0; j < 8; ++j) {
                fc[j] = qc; fs[j] = qs;
                if (j < 7) {
                    float tq = qc * c1 - qs * s1;
                    qs = fmaf(qc, s1, qs * c1);
                    qc = tq;
                }
            }
            uint32_t* pr = (uint32_t*)&pc[m];
            uint32_t* pi = (uint32_t*)&psn[m];
            #pragma unroll
            for (int p = 0; p < 4; ++p) {
                pr[p] = pkbf(fc[2 * p], fc[2 * p + 1]);
                pi[p] = pkbf(fs[2 * p], fs[2 * p + 1]);
            }
            if (m < 3) {
                float tp = pcv * c16 - ps * s16;
                ps  = fmaf(pcv, s16, ps * c16);
                pcv = tp;
            }
        }
    }

    // ---- final per-k rotation cis(pi*tx/128)
    float srR, crR; sincospif(tx * 0.0078125f, &srR, &crR);

    // ---- stage-2 rotors
    float rdi, rdr; sincospif(-ty * 0.25f, &rdi, &rdr);
    float cb[8], sb[8];
    {
        float bs, bc; sincospif(-ty * (float)(2 * hi - 64) * (1.0f / 64.0f), &bs, &bc);
        float qs4, qc4; sincospif(-ty * 0.0625f,   &qs4, &qc4);
        float os1, oc1; sincospif(-ty * 0.015625f, &os1, &oc1);
        float rc = bc, rs = bs;
        #pragma unroll
        for (int q = 0; q < 4; ++q) {
            cb[2 * q] = rc;  sb[2 * q] = rs;
            cb[2 * q + 1] = rc * oc1 - rs * os1;
            sb[2 * q + 1] = fmaf(rc, os1, rs * oc1);
            if (q < 3) {
                float tz = rc * qc4 - rs * qs4;
                rs = fmaf(rc, qs4, rs * qc4);
                rc = tz;
            }
        }
    }
    float ore = 0.f, oim = 0.f;

    // ---- per-lane LDS bases
    const int s7 = lane & 7;
    const int u  = s7 >> 1;
    const int v  = hi ^ (s7 & 1);
    const char* baseA = (const char*)&Bl[0] + 256 * l31 + 16 * v;
    const char* B0 = baseA + 32 * (0 ^ u);
    const char* B1 = baseA + 32 * (1 ^ u);
    const char* B2 = baseA + 32 * (2 ^ u);
    const char* B3 = baseA + 32 * (3 ^ u);
    const f32x16 ZER16 = {0.f,0.f,0.f,0.f,0.f,0.f,0.f,0.f,
                          0.f,0.f,0.f,0.f,0.f,0.f,0.f,0.f};

    __syncthreads();   // DMA drained; the ONLY barrier

    #pragma unroll 1
    for (int ct = 0; ct < 8; ++ct) {
        const int off = 8192 * ct;
        bf16x8 f0 = *(const bf16x8*)(B0 + off);          // plus-plane chunks
        bf16x8 f1 = *(const bf16x8*)(B1 + off);
        bf16x8 f2 = *(const bf16x8*)(B2 + off);
        bf16x8 f3 = *(const bf16x8*)(B3 + off);
        bf16x8 f4 = *(const bf16x8*)(B0 + off + 128);    // minus-plane chunks
        bf16x8 f5 = *(const bf16x8*)(B1 + off + 128);
        bf16x8 f6 = *(const bf16x8*)(B2 + off + 128);
        bf16x8 f7 = *(const bf16x8*)(B3 + off + 128);
        f32x16 a1, a2;
        __builtin_amdgcn_s_setprio(1);
        a1 = __builtin_amdgcn_mfma_f32_32x32x16_bf16(f0, pc[0],  ZER16, 0,0,0);
        a2 = __builtin_amdgcn_mfma_f32_32x32x16_bf16(f4, psn[0], ZER16, 0,0,0);
        a1 = __builtin_amdgcn_mfma_f32_32x32x16_bf16(f1, pc[1],  a1,    0,0,0);
        a2 = __builtin_amdgcn_mfma_f32_32x32x16_bf16(f5, psn[1], a2,    0,0,0);
        a1 = __builtin_amdgcn_mfma_f32_32x32x16_bf16(f2, pc[2],  a1,    0,0,0);
        a2 = __builtin_amdgcn_mfma_f32_32x32x16_bf16(f6, psn[2], a2,    0,0,0);
        a1 = __builtin_amdgcn_mfma_f32_32x32x16_bf16(f3, pc[3],  a1,    0,0,0);
        a2 = __builtin_amdgcn_mfma_f32_32x32x16_bf16(f7, psn[3], a2,    0,0,0);
        __builtin_amdgcn_s_setprio(0);
        // stage 2
        #pragma unroll
        for (int q = 0; q < 4; ++q) {
            #pragma unroll
            for (int j = 0; j < 2; ++j) {
                const int e = 4 * q + 2 * j;
                const int p = 2 * q + j;
                float Sre = a1[e]     - a2[e + 1];
                float Sim = a1[e + 1] + a2[e];
                ore = fmaf(Sre,  cb[p], ore);
                ore = fmaf(-Sim, sb[p], ore);
                oim = fmaf(Sre,  sb[p], oim);
                oim = fmaf(Sim,  cb[p], oim);
            }
        }
        // advance rotors (y += 16)
        #pragma unroll
        for (int p = 0; p < 8; ++p) {
            float tz = cb[p] * rdr - sb[p] * rdi;
            sb[p] = fmaf(cb[p], rdi, sb[p] * rdr);
            cb[p] = tz;
        }
    }

    // ---- epilogue: fold lane-halves, apply final rotation cis(pi*tx/128)
    {
        float r0 = ore + __shfl_xor(ore, 32);
        float i0 = oim + __shfl_xor(oim, 32);
        if (lane < 32) {
            out[(size_t)c * KPTS + k]                      = r0 * crR - i0 * srR;
            out[(size_t)NCH * KPTS + (size_t)c * KPTS + k] = fmaf(r0, srR, i0 * crR);
        }
    }
}

extern "C" void kernel_launch(void* const* d_in, const int* in_sizes, int n_in,
                              void* d_out, int out_size, void* d_ws, size_t ws_size,
                              hipStream_t stream)
{
    const float* img_real = (const float*)d_in[0];  // (8,128,128) fp32
    const float* img_imag = (const float*)d_in[1];  // (8,128,128) fp32
    const float* trj      = (const float*)d_in[2];  // (16384,2) fp32
    float* out = (float*)d_out;                      // planar: re block then im block
    unsigned short* B_pre = (unsigned short*)d_ws;   // 512 KB (folded)

    prep_kernel<<<64, 256, 0, stream>>>(img_real, img_imag, B_pre);
    nudft_mfma_kernel<<<dim3(64, 8), 512, 0, stream>>>(trj, B_pre, out);
}